// Round 9
// baseline (530.781 us; speedup 1.0000x reference)
//
#include <hip/hip_runtime.h>
#include <math.h>

#define D_MODEL 512
#define INNER 64
#define HEADS 8
#define BATCH 4
#define SEQ 2048
#define BHN (BATCH*HEADS)                 // 32
#define PER_MAT ((size_t)BHN*SEQ*INNER)   // 4194304 elements

typedef __attribute__((ext_vector_type(8))) short short8;   // 8 bf16 (4 VGPRs)
typedef __attribute__((ext_vector_type(4))) float floatx4;

// split fp32 -> bf16 hi (truncate) + bf16 lo (truncate of residual)
__device__ __forceinline__ void split_bf(float f, unsigned short& h, unsigned short& l) {
    unsigned int u = __float_as_uint(f);
    h = (unsigned short)(u >> 16);
    float hf = __uint_as_float(u & 0xffff0000u);
    l = (unsigned short)(__float_as_uint(f - hf) >> 16);
}

__device__ __forceinline__ void split4(const float* f, uint2& ph, uint2& pl) {
    unsigned int h[4], l[4];
#pragma unroll
    for (int j = 0; j < 4; ++j) {
        unsigned short hu, lu;
        split_bf(f[j], hu, lu);
        h[j] = hu; l[j] = lu;
    }
    ph.x = h[0] | (h[1] << 16); ph.y = h[2] | (h[3] << 16);
    pl.x = l[0] | (l[1] << 16); pl.y = l[2] | (l[3] << 16);
}

// ---------------------------------------------------------------------------
// Prep 0: X -> Xh/Xl bf16 (same layout).
// ---------------------------------------------------------------------------
__global__ __launch_bounds__(256) void split_x(const float* __restrict__ X,
                                               unsigned short* __restrict__ Xh,
                                               unsigned short* __restrict__ Xl) {
    size_t base = ((size_t)blockIdx.x * 256 + threadIdx.x) * 8;
    float4 a = *(const float4*)&X[base];
    float4 b = *(const float4*)&X[base + 4];
    uint2 h0, l0, h1, l1;
    split4((const float*)&a, h0, l0);
    split4((const float*)&b, h1, l1);
    *(uint4*)&Xh[base] = make_uint4(h0.x, h0.y, h1.x, h1.y);
    *(uint4*)&Xl[base] = make_uint4(l0.x, l0.y, l1.x, l1.y);
}

// ---------------------------------------------------------------------------
// Prep 1: W (24x512x64) -> Wt hi/lo bf16 [n=1536][k=512].
// ---------------------------------------------------------------------------
__global__ __launch_bounds__(256) void split_w(const float* __restrict__ kern,
                                               unsigned short* __restrict__ Wth,
                                               unsigned short* __restrict__ Wtl) {
    __shared__ float tile[64 * 65];
    const int t = threadIdx.x;
    const int mat = blockIdx.x, k0 = blockIdx.y * 64;
#pragma unroll
    for (int c = 0; c < 4; ++c) {
        int idx = t + c * 256;
        int kl = idx >> 4, i4 = idx & 15;
        float4 v = *(const float4*)&kern[((size_t)mat * 512 + k0 + kl) * 64 + i4 * 4];
        tile[(i4 * 4 + 0) * 65 + kl] = v.x;
        tile[(i4 * 4 + 1) * 65 + kl] = v.y;
        tile[(i4 * 4 + 2) * 65 + kl] = v.z;
        tile[(i4 * 4 + 3) * 65 + kl] = v.w;
    }
    __syncthreads();
    {
        int i = t >> 2, kq = t & 3;
        uint2 h0, l0, h1, l1, h2, l2, h3, l3;
        float f[16];
#pragma unroll
        for (int jj = 0; jj < 16; ++jj) f[jj] = tile[i * 65 + kq * 16 + jj];
        split4(f, h0, l0); split4(f + 4, h1, l1);
        split4(f + 8, h2, l2); split4(f + 12, h3, l3);
        size_t off = ((size_t)mat * 64 + i) * 512 + k0 + kq * 16;
        *(uint4*)&Wth[off]     = make_uint4(h0.x, h0.y, h1.x, h1.y);
        *(uint4*)&Wth[off + 8] = make_uint4(h2.x, h2.y, h3.x, h3.y);
        *(uint4*)&Wtl[off]     = make_uint4(l0.x, l0.y, l1.x, l1.y);
        *(uint4*)&Wtl[off + 8] = make_uint4(l2.x, l2.y, l3.x, l3.y);
    }
}

// ---------------------------------------------------------------------------
// Prep 2: HK (512x512) -> HKt hi/lo bf16 [n][k] (transpose).
// ---------------------------------------------------------------------------
__global__ __launch_bounds__(256) void split_hk(const float* __restrict__ HK,
                                                unsigned short* __restrict__ Hth,
                                                unsigned short* __restrict__ Htl) {
    __shared__ float tile[64 * 65];
    const int t = threadIdx.x;
    const int n0 = blockIdx.x * 64, k0 = blockIdx.y * 64;
#pragma unroll
    for (int c = 0; c < 4; ++c) {
        int idx = t + c * 256;
        int kl = idx >> 4, n4 = idx & 15;
        float4 v = *(const float4*)&HK[(size_t)(k0 + kl) * 512 + n0 + n4 * 4];
        tile[(n4 * 4 + 0) * 65 + kl] = v.x;
        tile[(n4 * 4 + 1) * 65 + kl] = v.y;
        tile[(n4 * 4 + 2) * 65 + kl] = v.z;
        tile[(n4 * 4 + 3) * 65 + kl] = v.w;
    }
    __syncthreads();
    {
        int i = t >> 2, kq = t & 3;
        uint2 h0, l0, h1, l1, h2, l2, h3, l3;
        float f[16];
#pragma unroll
        for (int jj = 0; jj < 16; ++jj) f[jj] = tile[i * 65 + kq * 16 + jj];
        split4(f, h0, l0); split4(f + 4, h1, l1);
        split4(f + 8, h2, l2); split4(f + 12, h3, l3);
        size_t off = (size_t)(n0 + i) * 512 + k0 + kq * 16;
        *(uint4*)&Hth[off]     = make_uint4(h0.x, h0.y, h1.x, h1.y);
        *(uint4*)&Hth[off + 8] = make_uint4(h2.x, h2.y, h3.x, h3.y);
        *(uint4*)&Htl[off]     = make_uint4(l0.x, l0.y, l1.x, l1.y);
        *(uint4*)&Htl[off + 8] = make_uint4(l2.x, l2.y, l3.x, l3.y);
    }
}

// ---------------------------------------------------------------------------
// Kernel 1: QKV projection, split-bf16 MFMA + register prefetch + XCD swizzle
// (all 12 n-blocks of one r-block land on one XCD -> A-tile L2-resident).
// ---------------------------------------------------------------------------
__global__ __launch_bounds__(256) void qkv_mfma(const unsigned short* __restrict__ Xh,
                                                const unsigned short* __restrict__ Xl,
                                                const unsigned short* __restrict__ Wth,
                                                const unsigned short* __restrict__ Wtl,
                                                unsigned short* __restrict__ Qh,
                                                unsigned short* __restrict__ Ql,
                                                unsigned short* __restrict__ Kh,
                                                unsigned short* __restrict__ Kl,
                                                unsigned short* __restrict__ Vth,
                                                unsigned short* __restrict__ Vtl) {
    __shared__ __align__(16) unsigned short smem[16384];   // 32 KB
    unsigned short* Ah = smem;            // [m][k] 128x32
    unsigned short* Al = smem + 4096;
    unsigned short* Bh = smem + 8192;     // [n][k] 128x32
    unsigned short* Bl = smem + 12288;

    const int t = threadIdx.x;
    const int w = t >> 6, lane = t & 63;
    const int quad = lane >> 4, l16 = lane & 15;
    const int wm = w & 1, wn = w >> 1;
    // XCD swizzle: bid = xcd + 8*(rsub*12 + nb); r_block = rsub*8 + xcd
    const int bid = blockIdx.x;
    const int xcd = bid & 7, rest = bid >> 3;
    const int nb = rest % 12, rsub = rest / 12;
    const int r0 = (rsub * 8 + xcd) * 128, n0 = nb * 128;

    const int arow = t >> 2, apart = t & 3;

    floatx4 acc[4][4];
#pragma unroll
    for (int mt = 0; mt < 4; ++mt)
#pragma unroll
        for (int nt = 0; nt < 4; ++nt) acc[mt][nt] = (floatx4)(0.f);

    uint4 pA[4], pB[4];
#pragma unroll
    for (int c = 0; c < 2; ++c) {
        size_t srcA = (size_t)(r0 + arow + c * 64) * 512 + apart * 8;
        pA[c * 2 + 0] = *(const uint4*)&Xh[srcA];
        pA[c * 2 + 1] = *(const uint4*)&Xl[srcA];
        size_t srcB = (size_t)(n0 + arow + c * 64) * 512 + apart * 8;
        pB[c * 2 + 0] = *(const uint4*)&Wth[srcB];
        pB[c * 2 + 1] = *(const uint4*)&Wtl[srcB];
    }

    for (int ko = 0; ko < 16; ++ko) {
        __syncthreads();
#pragma unroll
        for (int c = 0; c < 2; ++c) {
            int dst = (arow + c * 64) * 32 + apart * 8;
            *(uint4*)&Ah[dst] = pA[c * 2 + 0];
            *(uint4*)&Al[dst] = pA[c * 2 + 1];
            *(uint4*)&Bh[dst] = pB[c * 2 + 0];
            *(uint4*)&Bl[dst] = pB[c * 2 + 1];
        }
        if (ko + 1 < 16) {
            const int k0 = (ko + 1) * 32;
#pragma unroll
            for (int c = 0; c < 2; ++c) {
                size_t srcA = (size_t)(r0 + arow + c * 64) * 512 + k0 + apart * 8;
                pA[c * 2 + 0] = *(const uint4*)&Xh[srcA];
                pA[c * 2 + 1] = *(const uint4*)&Xl[srcA];
                size_t srcB = (size_t)(n0 + arow + c * 64) * 512 + k0 + apart * 8;
                pB[c * 2 + 0] = *(const uint4*)&Wth[srcB];
                pB[c * 2 + 1] = *(const uint4*)&Wtl[srcB];
            }
        }
        __syncthreads();

        short8 af[4], alf[4], bf[4], blf[4];
#pragma unroll
        for (int mt = 0; mt < 4; ++mt) {
            af[mt]  = *(const short8*)&Ah[(wm * 64 + mt * 16 + l16) * 32 + quad * 8];
            alf[mt] = *(const short8*)&Al[(wm * 64 + mt * 16 + l16) * 32 + quad * 8];
        }
#pragma unroll
        for (int nt = 0; nt < 4; ++nt) {
            bf[nt]  = *(const short8*)&Bh[(wn * 64 + nt * 16 + l16) * 32 + quad * 8];
            blf[nt] = *(const short8*)&Bl[(wn * 64 + nt * 16 + l16) * 32 + quad * 8];
        }
#pragma unroll
        for (int mt = 0; mt < 4; ++mt)
#pragma unroll
            for (int nt = 0; nt < 4; ++nt) {
                acc[mt][nt] = __builtin_amdgcn_mfma_f32_16x16x32_bf16(af[mt], bf[nt], acc[mt][nt], 0, 0, 0);
                acc[mt][nt] = __builtin_amdgcn_mfma_f32_16x16x32_bf16(af[mt], blf[nt], acc[mt][nt], 0, 0, 0);
                acc[mt][nt] = __builtin_amdgcn_mfma_f32_16x16x32_bf16(alf[mt], bf[nt], acc[mt][nt], 0, 0, 0);
            }
    }

    // Epilogue (verified R6/R7): wave-uniform mat, LDS repack, coalesced stores
    __syncthreads();
    const int mat = (n0 + wn * 64) >> 6;
    const int h = mat / 3, j = mat - 3 * h;
    const size_t bh = (size_t)(r0 >> 11) * HEADS + h;
    float* pw = (float*)smem + w * 1088;    // 16 x 68 fp32 per wave
    const float scale = (j == 0) ? 0.125f : 1.0f;

#pragma unroll 1
    for (int mt = 0; mt < 4; ++mt) {
        asm volatile("" ::: "memory");
#pragma unroll
        for (int nt = 0; nt < 4; ++nt)
#pragma unroll
            for (int r = 0; r < 4; ++r)
                pw[(quad * 4 + r) * 68 + nt * 16 + l16] = acc[mt][nt][r] * scale;
        asm volatile("s_waitcnt lgkmcnt(0)" ::: "memory");
        const int sbase = (r0 & 2047) + wm * 64 + mt * 16;
        if (j < 2) {
            unsigned short* dh = (j == 0) ? Qh : Kh;
            unsigned short* dl = (j == 0) ? Ql : Kl;
            float f[16];
            const float* pr = pw + l16 * 68 + quad * 16;
#pragma unroll
            for (int jj = 0; jj < 16; ++jj) f[jj] = pr[jj];
            uint2 h0, l0, h1, l1, h2, l2, h3, l3;
            split4(f, h0, l0); split4(f + 4, h1, l1);
            split4(f + 8, h2, l2); split4(f + 12, h3, l3);
            size_t off = (bh * SEQ + sbase + l16) * 64 + quad * 16;
            *(uint4*)&dh[off]     = make_uint4(h0.x, h0.y, h1.x, h1.y);
            *(uint4*)&dh[off + 8] = make_uint4(h2.x, h2.y, h3.x, h3.y);
            *(uint4*)&dl[off]     = make_uint4(l0.x, l0.y, l1.x, l1.y);
            *(uint4*)&dl[off + 8] = make_uint4(l2.x, l2.y, l3.x, l3.y);
        } else {
            float f[16];
#pragma unroll
            for (int ss = 0; ss < 16; ++ss) f[ss] = pw[ss * 68 + lane];
            uint2 h0, l0, h1, l1, h2, l2, h3, l3;
            split4(f, h0, l0); split4(f + 4, h1, l1);
            split4(f + 8, h2, l2); split4(f + 12, h3, l3);
            size_t off = (bh * 64 + lane) * SEQ + sbase;
            *(uint4*)&Vth[off]     = make_uint4(h0.x, h0.y, h1.x, h1.y);
            *(uint4*)&Vth[off + 8] = make_uint4(h2.x, h2.y, h3.x, h3.y);
            *(uint4*)&Vtl[off]     = make_uint4(l0.x, l0.y, l1.x, l1.y);
            *(uint4*)&Vtl[off + 8] = make_uint4(l2.x, l2.y, l3.x, l3.y);
        }
    }
}

// ---------------------------------------------------------------------------
// Kernel 2: flash attention — EXACT R7 body (passed twice). 16x16x32 MFMAs,
// dedicated P scratch, register prefetch of next K/V tile, 2 barriers/tile.
// ---------------------------------------------------------------------------
__global__ __launch_bounds__(256) void attn_mfma(
        const unsigned short* __restrict__ Qh_g, const unsigned short* __restrict__ Ql_g,
        const unsigned short* __restrict__ Kh_g, const unsigned short* __restrict__ Kl_g,
        const unsigned short* __restrict__ Vth_g, const unsigned short* __restrict__ Vtl_g,
        unsigned short* __restrict__ Oh_g, unsigned short* __restrict__ Ol_g) {
    __shared__ unsigned short Ksh[64 * 72];
    __shared__ unsigned short Ksl[64 * 72];
    __shared__ unsigned short Vsh[64 * 72];        // [dim][key]
    __shared__ unsigned short Vsl[64 * 72];
    __shared__ float Pw[4][32 * 36];               // per-wave P scratch (dedicated)

    const int t = threadIdx.x;
    const int w = t >> 6, lane = t & 63;
    const int quad = lane >> 4, l16 = lane & 15;
    const int bh = blockIdx.x;
    const int qbase = blockIdx.y * 128 + w * 32;
    float* pw = &Pw[w][0];

    short8 qhf[2][2], qlf[2][2];
#pragma unroll
    for (int qg = 0; qg < 2; ++qg) {
        const unsigned short* p = Qh_g + ((size_t)bh * SEQ + qbase + qg * 16 + l16) * INNER + quad * 8;
        qhf[qg][0] = *(const short8*)p;
        qhf[qg][1] = *(const short8*)(p + 32);
        const unsigned short* p2 = Ql_g + ((size_t)bh * SEQ + qbase + qg * 16 + l16) * INNER + quad * 8;
        qlf[qg][0] = *(const short8*)p2;
        qlf[qg][1] = *(const short8*)(p2 + 32);
    }

    floatx4 o[2][4];
#pragma unroll
    for (int qg = 0; qg < 2; ++qg)
#pragma unroll
        for (int nt = 0; nt < 4; ++nt) o[qg][nt] = (floatx4)(0.f);
    float mrun[2] = {-1e30f, -1e30f};
    float lrun[2] = {0.f, 0.f};

    const uint4* ksrc_h = (const uint4*)(Kh_g + (size_t)bh * SEQ * INNER);
    const uint4* ksrc_l = (const uint4*)(Kl_g + (size_t)bh * SEQ * INNER);
    const uint4* vsrc_h = (const uint4*)(Vth_g + (size_t)bh * INNER * SEQ);
    const uint4* vsrc_l = (const uint4*)(Vtl_g + (size_t)bh * INNER * SEQ);

    // prefetch tile 0 into registers
    uint4 pkh[2], pkl[2], pvh[2], pvl[2];
#pragma unroll
    for (int ii = 0; ii < 2; ++ii) {
        int id = t + ii * 256, row = id >> 3, part = id & 7;
        pkh[ii] = ksrc_h[id];
        pkl[ii] = ksrc_l[id];
        pvh[ii] = vsrc_h[row * 256 + part];
        pvl[ii] = vsrc_l[row * 256 + part];
    }

    for (int kt = 0; kt < 32; ++kt) {
        __syncthreads();   // (A) prior tile's readers done
#pragma unroll
        for (int ii = 0; ii < 2; ++ii) {
            int id = t + ii * 256, row = id >> 3, part = id & 7;
            int dst = row * 72 + part * 8;
            *(uint4*)&Ksh[dst] = pkh[ii];
            *(uint4*)&Ksl[dst] = pkl[ii];
            *(uint4*)&Vsh[dst] = pvh[ii];
            *(uint4*)&Vsl[dst] = pvl[ii];
        }
        if (kt + 1 < 32) {
#pragma unroll
            for (int ii = 0; ii < 2; ++ii) {
                int id = t + ii * 256, row = id >> 3, part = id & 7;
                pkh[ii] = ksrc_h[(kt + 1) * 512 + id];
                pkl[ii] = ksrc_l[(kt + 1) * 512 + id];
                pvh[ii] = vsrc_h[row * 256 + (kt + 1) * 8 + part];
                pvl[ii] = vsrc_l[row * 256 + (kt + 1) * 8 + part];
            }
        }
        __syncthreads();   // (B) staging visible

        floatx4 s[2][4];
#pragma unroll
        for (int st = 0; st < 4; ++st) {
            const unsigned short* ka = &Ksh[(st * 16 + l16) * 72 + quad * 8];
            const unsigned short* kb = &Ksl[(st * 16 + l16) * 72 + quad * 8];
            short8 kh0 = *(const short8*)ka;
            short8 kh1 = *(const short8*)(ka + 32);
            short8 kl0 = *(const short8*)kb;
            short8 kl1 = *(const short8*)(kb + 32);
#pragma unroll
            for (int qg = 0; qg < 2; ++qg) {
                floatx4 a = (floatx4)(0.f);
                a = __builtin_amdgcn_mfma_f32_16x16x32_bf16(kh0, qhf[qg][0], a, 0, 0, 0);
                a = __builtin_amdgcn_mfma_f32_16x16x32_bf16(kh1, qhf[qg][1], a, 0, 0, 0);
                a = __builtin_amdgcn_mfma_f32_16x16x32_bf16(kl0, qhf[qg][0], a, 0, 0, 0);
                a = __builtin_amdgcn_mfma_f32_16x16x32_bf16(kl1, qhf[qg][1], a, 0, 0, 0);
                a = __builtin_amdgcn_mfma_f32_16x16x32_bf16(kh0, qlf[qg][0], a, 0, 0, 0);
                a = __builtin_amdgcn_mfma_f32_16x16x32_bf16(kh1, qlf[qg][1], a, 0, 0, 0);
                s[qg][st] = a;
            }
        }

#pragma unroll
        for (int qg = 0; qg < 2; ++qg) {
            float mloc = s[qg][0][0];
#pragma unroll
            for (int st = 0; st < 4; ++st)
#pragma unroll
                for (int r = 0; r < 4; ++r) mloc = fmaxf(mloc, s[qg][st][r]);
            mloc = fmaxf(mloc, __shfl_xor(mloc, 16));
            mloc = fmaxf(mloc, __shfl_xor(mloc, 32));
            float mn = fmaxf(mrun[qg], mloc);
            float alpha = __expf(mrun[qg] - mn);
            mrun[qg] = mn;
            float rs = 0.f;
#pragma unroll
            for (int st = 0; st < 4; ++st)
#pragma unroll
                for (int r = 0; r < 4; ++r) {
                    float p = __expf(s[qg][st][r] - mn);
                    s[qg][st][r] = p;
                    rs += p;
                }
            rs += __shfl_xor(rs, 16);
            rs += __shfl_xor(rs, 32);
            lrun[qg] = lrun[qg] * alpha + rs;
#pragma unroll
            for (int nt = 0; nt < 4; ++nt) o[qg][nt] = o[qg][nt] * alpha;
        }

#pragma unroll
        for (int half = 0; half < 2; ++half) {
            asm volatile("" ::: "memory");
#pragma unroll
            for (int qg = 0; qg < 2; ++qg)
#pragma unroll
                for (int st2 = 0; st2 < 2; ++st2) {
                    int st = half * 2 + st2;
                    float4 v = make_float4(s[qg][st][0], s[qg][st][1],
                                           s[qg][st][2], s[qg][st][3]);
                    *(float4*)&pw[(qg * 16 + l16) * 36 + st2 * 16 + quad * 4] = v;
                }
            asm volatile("s_waitcnt lgkmcnt(0)" ::: "memory");

            short8 phf[2], plf[2];
#pragma unroll
            for (int qg = 0; qg < 2; ++qg) {
                const float* pr = &pw[(qg * 16 + l16) * 36 + quad * 8];
                float4 pa = *(const float4*)pr;
                float4 pb = *(const float4*)(pr + 4);
                float pv[8] = {pa.x, pa.y, pa.z, pa.w, pb.x, pb.y, pb.z, pb.w};
#pragma unroll
                for (int jj = 0; jj < 8; ++jj) {
                    unsigned short hu, lu;
                    split_bf(pv[jj], hu, lu);
                    phf[qg][jj] = (short)hu;
                    plf[qg][jj] = (short)lu;
                }
            }
#pragma unroll
            for (int nt = 0; nt < 4; ++nt) {
                const unsigned short* va = &Vsh[(nt * 16 + l16) * 72 + half * 32 + quad * 8];
                const unsigned short* vb = &Vsl[(nt * 16 + l16) * 72 + half * 32 + quad * 8];
                short8 vh = *(const short8*)va;
                short8 vl = *(const short8*)vb;
#pragma unroll
                for (int qg = 0; qg < 2; ++qg) {
                    o[qg][nt] = __builtin_amdgcn_mfma_f32_16x16x32_bf16(vh, phf[qg], o[qg][nt], 0, 0, 0);
                    o[qg][nt] = __builtin_amdgcn_mfma_f32_16x16x32_bf16(vh, plf[qg], o[qg][nt], 0, 0, 0);
                    o[qg][nt] = __builtin_amdgcn_mfma_f32_16x16x32_bf16(vl, phf[qg], o[qg][nt], 0, 0, 0);
                }
            }
        }
    }

    // epilogue: split-bf16 O
#pragma unroll
    for (int qg = 0; qg < 2; ++qg) {
        float inv = 1.f / lrun[qg];
        size_t row = (size_t)bh * SEQ + qbase + qg * 16 + l16;
#pragma unroll
        for (int nt = 0; nt < 4; ++nt) {
            float f[4] = {o[qg][nt][0] * inv, o[qg][nt][1] * inv,
                          o[qg][nt][2] * inv, o[qg][nt][3] * inv};
            uint2 ph, pl;
            split4(f, ph, pl);
            size_t off = row * 64 + nt * 16 + quad * 4;
            *(uint2*)&Oh_g[off] = ph;
            *(uint2*)&Ol_g[off] = pl;
        }
    }
}

// ---------------------------------------------------------------------------
// Kernel 3: output projection, split-bf16 MFMA + prefetch + XCD swizzle.
// 64x128 tiles; grid 512 = 2 blocks/CU.
// ---------------------------------------------------------------------------
__global__ __launch_bounds__(256) void out_proj_mfma(const unsigned short* __restrict__ Oh,
                                                     const unsigned short* __restrict__ Ol,
                                                     const unsigned short* __restrict__ Hth,
                                                     const unsigned short* __restrict__ Htl,
                                                     float* __restrict__ Y) {
    __shared__ __align__(16) unsigned short smem[12288];   // 24.6 KB
    unsigned short* Ah = smem;            // 64 x 32
    unsigned short* Al = smem + 2048;
    unsigned short* Bh = smem + 4096;     // 128 x 32
    unsigned short* Bl = smem + 8192;

    const int t = threadIdx.x;
    const int w = t >> 6, lane = t & 63;
    const int quad = lane >> 4, l16 = lane & 15;
    const int wm = w & 1, wn = w >> 1;
    const int bid = blockIdx.x;
    const int xcd = bid & 7, rest = bid >> 3;
    const int nb = rest & 3, rsub = rest >> 2;
    const int r0 = (rsub * 8 + xcd) * 64, n0 = nb * 128;
    const int b = r0 >> 11;

    const int arow = t >> 2, apart = t & 3;

    floatx4 acc[2][4];
#pragma unroll
    for (int mt = 0; mt < 2; ++mt)
#pragma unroll
        for (int nt = 0; nt < 4; ++nt) acc[mt][nt] = (floatx4)(0.f);

    uint4 pA[2], pB[4];
    {
        const size_t bh0 = (size_t)b * HEADS;   // ko=0 -> h=0, d0=0
        size_t srcA = (bh0 * SEQ + (r0 & 2047) + arow) * 64 + apart * 8;
        pA[0] = *(const uint4*)&Oh[srcA];
        pA[1] = *(const uint4*)&Ol[srcA];
#pragma unroll
        for (int c = 0; c < 2; ++c) {
            size_t srcB = (size_t)(n0 + arow + c * 64) * 512 + apart * 8;
            pB[c * 2 + 0] = *(const uint4*)&Hth[srcB];
            pB[c * 2 + 1] = *(const uint4*)&Htl[srcB];
        }
    }

    for (int ko = 0; ko < 16; ++ko) {
        __syncthreads();
        {
            int dst = arow * 32 + apart * 8;
            *(uint4*)&Ah[dst] = pA[0];
            *(uint4*)&Al[dst] = pA[1];
#pragma unroll
            for (int c = 0; c < 2; ++c) {
                int dstb = (arow + c * 64) * 32 + apart * 8;
                *(uint4*)&Bh[dstb] = pB[c * 2 + 0];
                *(uint4*)&Bl[dstb] = pB[c * 2 + 1];
            }
        }
        if (ko + 1 < 16) {
            const int kon = ko + 1;
            const int h = kon >> 1, d0 = (kon & 1) * 32;
            const size_t bh = (size_t)b * HEADS + h;
            size_t srcA = (bh * SEQ + (r0 & 2047) + arow) * 64 + d0 + apart * 8;
            pA[0] = *(const uint4*)&Oh[srcA];
            pA[1] = *(const uint4*)&Ol[srcA];
            const int k0 = kon * 32;
#pragma unroll
            for (int c = 0; c < 2; ++c) {
                size_t srcB = (size_t)(n0 + arow + c * 64) * 512 + k0 + apart * 8;
                pB[c * 2 + 0] = *(const uint4*)&Hth[srcB];
                pB[c * 2 + 1] = *(const uint4*)&Htl[srcB];
            }
        }
        __syncthreads();

        short8 af[2], alf[2], bf[4], blf[4];
#pragma unroll
        for (int mt = 0; mt < 2; ++mt) {
            af[mt]  = *(const short8*)&Ah[(wm * 32 + mt * 16 + l16) * 32 + quad * 8];
            alf[mt] = *(const short8*)&Al[(wm * 32 + mt * 16 + l16) * 32 + quad * 8];
        }
#pragma unroll
        for (int nt = 0; nt < 4; ++nt) {
            bf[nt]  = *(const short8*)&Bh[(wn * 64 + nt * 16 + l16) * 32 + quad * 8];
            blf[nt] = *(const short8*)&Bl[(wn * 64 + nt * 16 + l16) * 32 + quad * 8];
        }
#pragma unroll
        for (int mt = 0; mt < 2; ++mt)
#pragma unroll
            for (int nt = 0; nt < 4; ++nt) {
                acc[mt][nt] = __builtin_amdgcn_mfma_f32_16x16x32_bf16(af[mt], bf[nt], acc[mt][nt], 0, 0, 0);
                acc[mt][nt] = __builtin_amdgcn_mfma_f32_16x16x32_bf16(af[mt], blf[nt], acc[mt][nt], 0, 0, 0);
                acc[mt][nt] = __builtin_amdgcn_mfma_f32_16x16x32_bf16(alf[mt], bf[nt], acc[mt][nt], 0, 0, 0);
            }
    }

#pragma unroll
    for (int mt = 0; mt < 2; ++mt)
#pragma unroll
        for (int nt = 0; nt < 4; ++nt)
#pragma unroll
            for (int r = 0; r < 4; ++r)
                Y[(size_t)(r0 + wm * 32 + mt * 16 + quad * 4 + r) * 512 +
                  n0 + wn * 64 + nt * 16 + l16] = acc[mt][nt][r];
}

extern "C" void kernel_launch(void* const* d_in, const int* in_sizes, int n_in,
                              void* d_out, int out_size, void* d_ws, size_t ws_size,
                              hipStream_t stream) {
    const float* x    = (const float*)d_in[0];
    const float* kern = (const float*)d_in[1];
    const float* hk   = (const float*)d_in[2];
    float* y = (float*)d_out;

    unsigned short* Qh  = (unsigned short*)d_ws;
    unsigned short* Ql  = Qh + PER_MAT;
    unsigned short* Kh  = Qh + 2 * PER_MAT;
    unsigned short* Kl  = Qh + 3 * PER_MAT;
    unsigned short* Vth = Qh + 4 * PER_MAT;
    unsigned short* Vtl = Qh + 5 * PER_MAT;
    unsigned short* Oh  = Qh + 6 * PER_MAT;
    unsigned short* Ol  = Qh + 7 * PER_MAT;
    unsigned short* Xh  = Oh;   // alias: X dead before attn writes O
    unsigned short* Xl  = Ol;
    unsigned short* Wth = Qh + 8 * PER_MAT;
    unsigned short* Wtl = Wth + (size_t)1536 * 512;
    unsigned short* Hth = Wtl + (size_t)1536 * 512;
    unsigned short* Htl = Hth + (size_t)512 * 512;

    split_x<<<dim3(2048), 256, 0, stream>>>(x, Xh, Xl);
    split_w<<<dim3(24, 8), 256, 0, stream>>>(kern, Wth, Wtl);
    split_hk<<<dim3(8, 8), 256, 0, stream>>>(hk, Hth, Htl);
    qkv_mfma<<<dim3(768), 256, 0, stream>>>(Xh, Xl, Wth, Wtl, Qh, Ql, Kh, Kl, Vth, Vtl);
    attn_mfma<<<dim3(32, 16), 256, 0, stream>>>(Qh, Ql, Kh, Kl, Vth, Vtl, Oh, Ol);
    out_proj_mfma<<<dim3(512), 256, 0, stream>>>(Oh, Ol, Hth, Htl, y);
}

// Round 10
// 416.710 us; speedup vs baseline: 1.2737x; 1.2737x over previous
//
#include <hip/hip_runtime.h>
#include <math.h>

#define D_MODEL 512
#define INNER 64
#define HEADS 8
#define BATCH 4
#define SEQ 2048
#define BHN (BATCH*HEADS)                 // 32
#define PER_MAT ((size_t)BHN*SEQ*INNER)   // 4194304 elements

typedef __attribute__((ext_vector_type(8))) short short8;   // 8 bf16 (4 VGPRs)
typedef __attribute__((ext_vector_type(4))) float floatx4;

// split fp32 -> bf16 hi (truncate) + bf16 lo (truncate of residual)
__device__ __forceinline__ void split_bf(float f, unsigned short& h, unsigned short& l) {
    unsigned int u = __float_as_uint(f);
    h = (unsigned short)(u >> 16);
    float hf = __uint_as_float(u & 0xffff0000u);
    l = (unsigned short)(__float_as_uint(f - hf) >> 16);
}

__device__ __forceinline__ void split4(const float* f, uint2& ph, uint2& pl) {
    unsigned int h[4], l[4];
#pragma unroll
    for (int j = 0; j < 4; ++j) {
        unsigned short hu, lu;
        split_bf(f[j], hu, lu);
        h[j] = hu; l[j] = lu;
    }
    ph.x = h[0] | (h[1] << 16); ph.y = h[2] | (h[3] << 16);
    pl.x = l[0] | (l[1] << 16); pl.y = l[2] | (l[3] << 16);
}

// ---------------------------------------------------------------------------
// Prep 0: X -> Xh/Xl bf16 (same layout).
// ---------------------------------------------------------------------------
__global__ __launch_bounds__(256) void split_x(const float* __restrict__ X,
                                               unsigned short* __restrict__ Xh,
                                               unsigned short* __restrict__ Xl) {
    size_t base = ((size_t)blockIdx.x * 256 + threadIdx.x) * 8;
    float4 a = *(const float4*)&X[base];
    float4 b = *(const float4*)&X[base + 4];
    uint2 h0, l0, h1, l1;
    split4((const float*)&a, h0, l0);
    split4((const float*)&b, h1, l1);
    *(uint4*)&Xh[base] = make_uint4(h0.x, h0.y, h1.x, h1.y);
    *(uint4*)&Xl[base] = make_uint4(l0.x, l0.y, l1.x, l1.y);
}

// ---------------------------------------------------------------------------
// Prep 1: W (24x512x64) -> Wt hi/lo bf16 [n=1536][k=512].
// ---------------------------------------------------------------------------
__global__ __launch_bounds__(256) void split_w(const float* __restrict__ kern,
                                               unsigned short* __restrict__ Wth,
                                               unsigned short* __restrict__ Wtl) {
    __shared__ float tile[64 * 65];
    const int t = threadIdx.x;
    const int mat = blockIdx.x, k0 = blockIdx.y * 64;
#pragma unroll
    for (int c = 0; c < 4; ++c) {
        int idx = t + c * 256;
        int kl = idx >> 4, i4 = idx & 15;
        float4 v = *(const float4*)&kern[((size_t)mat * 512 + k0 + kl) * 64 + i4 * 4];
        tile[(i4 * 4 + 0) * 65 + kl] = v.x;
        tile[(i4 * 4 + 1) * 65 + kl] = v.y;
        tile[(i4 * 4 + 2) * 65 + kl] = v.z;
        tile[(i4 * 4 + 3) * 65 + kl] = v.w;
    }
    __syncthreads();
    {
        int i = t >> 2, kq = t & 3;
        uint2 h0, l0, h1, l1, h2, l2, h3, l3;
        float f[16];
#pragma unroll
        for (int jj = 0; jj < 16; ++jj) f[jj] = tile[i * 65 + kq * 16 + jj];
        split4(f, h0, l0); split4(f + 4, h1, l1);
        split4(f + 8, h2, l2); split4(f + 12, h3, l3);
        size_t off = ((size_t)mat * 64 + i) * 512 + k0 + kq * 16;
        *(uint4*)&Wth[off]     = make_uint4(h0.x, h0.y, h1.x, h1.y);
        *(uint4*)&Wth[off + 8] = make_uint4(h2.x, h2.y, h3.x, h3.y);
        *(uint4*)&Wtl[off]     = make_uint4(l0.x, l0.y, l1.x, l1.y);
        *(uint4*)&Wtl[off + 8] = make_uint4(l2.x, l2.y, l3.x, l3.y);
    }
}

// ---------------------------------------------------------------------------
// Prep 2: HK (512x512) -> HKt hi/lo bf16 [n][k] (transpose).
// ---------------------------------------------------------------------------
__global__ __launch_bounds__(256) void split_hk(const float* __restrict__ HK,
                                                unsigned short* __restrict__ Hth,
                                                unsigned short* __restrict__ Htl) {
    __shared__ float tile[64 * 65];
    const int t = threadIdx.x;
    const int n0 = blockIdx.x * 64, k0 = blockIdx.y * 64;
#pragma unroll
    for (int c = 0; c < 4; ++c) {
        int idx = t + c * 256;
        int kl = idx >> 4, n4 = idx & 15;
        float4 v = *(const float4*)&HK[(size_t)(k0 + kl) * 512 + n0 + n4 * 4];
        tile[(n4 * 4 + 0) * 65 + kl] = v.x;
        tile[(n4 * 4 + 1) * 65 + kl] = v.y;
        tile[(n4 * 4 + 2) * 65 + kl] = v.z;
        tile[(n4 * 4 + 3) * 65 + kl] = v.w;
    }
    __syncthreads();
    {
        int i = t >> 2, kq = t & 3;
        uint2 h0, l0, h1, l1, h2, l2, h3, l3;
        float f[16];
#pragma unroll
        for (int jj = 0; jj < 16; ++jj) f[jj] = tile[i * 65 + kq * 16 + jj];
        split4(f, h0, l0); split4(f + 4, h1, l1);
        split4(f + 8, h2, l2); split4(f + 12, h3, l3);
        size_t off = (size_t)(n0 + i) * 512 + k0 + kq * 16;
        *(uint4*)&Hth[off]     = make_uint4(h0.x, h0.y, h1.x, h1.y);
        *(uint4*)&Hth[off + 8] = make_uint4(h2.x, h2.y, h3.x, h3.y);
        *(uint4*)&Htl[off]     = make_uint4(l0.x, l0.y, l1.x, l1.y);
        *(uint4*)&Htl[off + 8] = make_uint4(l2.x, l2.y, l3.x, l3.y);
    }
}

// ---------------------------------------------------------------------------
// Kernel 1: QKV projection, split-bf16 MFMA. R7-style direct global->LDS
// staging (NO register prefetch: R9's prefetch regs spilled to scratch,
// 1.27 GB HBM writes). __launch_bounds__(256,2): 256-reg budget, no spill.
// XCD swizzle kept: all 12 n-blocks of an X-row-slab land on one XCD.
// ---------------------------------------------------------------------------
__global__ __launch_bounds__(256, 2) void qkv_mfma(const unsigned short* __restrict__ Xh,
                                                   const unsigned short* __restrict__ Xl,
                                                   const unsigned short* __restrict__ Wth,
                                                   const unsigned short* __restrict__ Wtl,
                                                   unsigned short* __restrict__ Qh,
                                                   unsigned short* __restrict__ Ql,
                                                   unsigned short* __restrict__ Kh,
                                                   unsigned short* __restrict__ Kl,
                                                   unsigned short* __restrict__ Vth,
                                                   unsigned short* __restrict__ Vtl) {
    __shared__ __align__(16) unsigned short smem[16384];   // 32 KB
    unsigned short* Ah = smem;            // [m][k] 128x32
    unsigned short* Al = smem + 4096;
    unsigned short* Bh = smem + 8192;     // [n][k] 128x32
    unsigned short* Bl = smem + 12288;

    const int t = threadIdx.x;
    const int w = t >> 6, lane = t & 63;
    const int quad = lane >> 4, l16 = lane & 15;
    const int wm = w & 1, wn = w >> 1;
    // XCD swizzle: bid = xcd + 8*(rsub*12 + nb); r_block = rsub*8 + xcd
    const int bid = blockIdx.x;
    const int xcd = bid & 7, rest = bid >> 3;
    const int nb = rest % 12, rsub = rest / 12;
    const int r0 = (rsub * 8 + xcd) * 128, n0 = nb * 128;

    const int arow = t >> 2, apart = t & 3;

    floatx4 acc[4][4];
#pragma unroll
    for (int mt = 0; mt < 4; ++mt)
#pragma unroll
        for (int nt = 0; nt < 4; ++nt) acc[mt][nt] = (floatx4)(0.f);

    for (int ko = 0; ko < 16; ++ko) {
        const int k0 = ko * 32;
        __syncthreads();
#pragma unroll
        for (int c = 0; c < 2; ++c) {
            int row = arow + c * 64;
            size_t srcA = (size_t)(r0 + row) * 512 + k0 + apart * 8;
            int dst = row * 32 + apart * 8;
            *(uint4*)&Ah[dst] = *(const uint4*)&Xh[srcA];
            *(uint4*)&Al[dst] = *(const uint4*)&Xl[srcA];
            size_t srcB = (size_t)(n0 + row) * 512 + k0 + apart * 8;
            *(uint4*)&Bh[dst] = *(const uint4*)&Wth[srcB];
            *(uint4*)&Bl[dst] = *(const uint4*)&Wtl[srcB];
        }
        __syncthreads();

        short8 af[4], alf[4], bf[4], blf[4];
#pragma unroll
        for (int mt = 0; mt < 4; ++mt) {
            af[mt]  = *(const short8*)&Ah[(wm * 64 + mt * 16 + l16) * 32 + quad * 8];
            alf[mt] = *(const short8*)&Al[(wm * 64 + mt * 16 + l16) * 32 + quad * 8];
        }
#pragma unroll
        for (int nt = 0; nt < 4; ++nt) {
            bf[nt]  = *(const short8*)&Bh[(wn * 64 + nt * 16 + l16) * 32 + quad * 8];
            blf[nt] = *(const short8*)&Bl[(wn * 64 + nt * 16 + l16) * 32 + quad * 8];
        }
#pragma unroll
        for (int mt = 0; mt < 4; ++mt)
#pragma unroll
            for (int nt = 0; nt < 4; ++nt) {
                acc[mt][nt] = __builtin_amdgcn_mfma_f32_16x16x32_bf16(af[mt], bf[nt], acc[mt][nt], 0, 0, 0);
                acc[mt][nt] = __builtin_amdgcn_mfma_f32_16x16x32_bf16(af[mt], blf[nt], acc[mt][nt], 0, 0, 0);
                acc[mt][nt] = __builtin_amdgcn_mfma_f32_16x16x32_bf16(alf[mt], bf[nt], acc[mt][nt], 0, 0, 0);
            }
    }

    // Epilogue (verified R6/R7): wave-uniform mat, LDS repack, coalesced stores
    __syncthreads();
    const int mat = (n0 + wn * 64) >> 6;
    const int h = mat / 3, j = mat - 3 * h;
    const size_t bh = (size_t)(r0 >> 11) * HEADS + h;
    float* pw = (float*)smem + w * 1088;    // 16 x 68 fp32 per wave
    const float scale = (j == 0) ? 0.125f : 1.0f;

#pragma unroll 1
    for (int mt = 0; mt < 4; ++mt) {
        asm volatile("" ::: "memory");
#pragma unroll
        for (int nt = 0; nt < 4; ++nt)
#pragma unroll
            for (int r = 0; r < 4; ++r)
                pw[(quad * 4 + r) * 68 + nt * 16 + l16] = acc[mt][nt][r] * scale;
        asm volatile("s_waitcnt lgkmcnt(0)" ::: "memory");
        const int sbase = (r0 & 2047) + wm * 64 + mt * 16;
        if (j < 2) {
            unsigned short* dh = (j == 0) ? Qh : Kh;
            unsigned short* dl = (j == 0) ? Ql : Kl;
            float f[16];
            const float* pr = pw + l16 * 68 + quad * 16;
#pragma unroll
            for (int jj = 0; jj < 16; ++jj) f[jj] = pr[jj];
            uint2 h0, l0, h1, l1, h2, l2, h3, l3;
            split4(f, h0, l0); split4(f + 4, h1, l1);
            split4(f + 8, h2, l2); split4(f + 12, h3, l3);
            size_t off = (bh * SEQ + sbase + l16) * 64 + quad * 16;
            *(uint4*)&dh[off]     = make_uint4(h0.x, h0.y, h1.x, h1.y);
            *(uint4*)&dh[off + 8] = make_uint4(h2.x, h2.y, h3.x, h3.y);
            *(uint4*)&dl[off]     = make_uint4(l0.x, l0.y, l1.x, l1.y);
            *(uint4*)&dl[off + 8] = make_uint4(l2.x, l2.y, l3.x, l3.y);
        } else {
            float f[16];
#pragma unroll
            for (int ss = 0; ss < 16; ++ss) f[ss] = pw[ss * 68 + lane];
            uint2 h0, l0, h1, l1, h2, l2, h3, l3;
            split4(f, h0, l0); split4(f + 4, h1, l1);
            split4(f + 8, h2, l2); split4(f + 12, h3, l3);
            size_t off = (bh * 64 + lane) * SEQ + sbase;
            *(uint4*)&Vth[off]     = make_uint4(h0.x, h0.y, h1.x, h1.y);
            *(uint4*)&Vth[off + 8] = make_uint4(h2.x, h2.y, h3.x, h3.y);
            *(uint4*)&Vtl[off]     = make_uint4(l0.x, l0.y, l1.x, l1.y);
            *(uint4*)&Vtl[off + 8] = make_uint4(l2.x, l2.y, l3.x, l3.y);
        }
    }
}

// ---------------------------------------------------------------------------
// Kernel 2: flash attention — EXACT R7 body (passed 3x at ~183 µs).
// ---------------------------------------------------------------------------
__global__ __launch_bounds__(256) void attn_mfma(
        const unsigned short* __restrict__ Qh_g, const unsigned short* __restrict__ Ql_g,
        const unsigned short* __restrict__ Kh_g, const unsigned short* __restrict__ Kl_g,
        const unsigned short* __restrict__ Vth_g, const unsigned short* __restrict__ Vtl_g,
        unsigned short* __restrict__ Oh_g, unsigned short* __restrict__ Ol_g) {
    __shared__ unsigned short Ksh[64 * 72];
    __shared__ unsigned short Ksl[64 * 72];
    __shared__ unsigned short Vsh[64 * 72];        // [dim][key]
    __shared__ unsigned short Vsl[64 * 72];
    __shared__ float Pw[4][32 * 36];               // per-wave P scratch (dedicated)

    const int t = threadIdx.x;
    const int w = t >> 6, lane = t & 63;
    const int quad = lane >> 4, l16 = lane & 15;
    const int bh = blockIdx.x;
    const int qbase = blockIdx.y * 128 + w * 32;
    float* pw = &Pw[w][0];

    short8 qhf[2][2], qlf[2][2];
#pragma unroll
    for (int qg = 0; qg < 2; ++qg) {
        const unsigned short* p = Qh_g + ((size_t)bh * SEQ + qbase + qg * 16 + l16) * INNER + quad * 8;
        qhf[qg][0] = *(const short8*)p;
        qhf[qg][1] = *(const short8*)(p + 32);
        const unsigned short* p2 = Ql_g + ((size_t)bh * SEQ + qbase + qg * 16 + l16) * INNER + quad * 8;
        qlf[qg][0] = *(const short8*)p2;
        qlf[qg][1] = *(const short8*)(p2 + 32);
    }

    floatx4 o[2][4];
#pragma unroll
    for (int qg = 0; qg < 2; ++qg)
#pragma unroll
        for (int nt = 0; nt < 4; ++nt) o[qg][nt] = (floatx4)(0.f);
    float mrun[2] = {-1e30f, -1e30f};
    float lrun[2] = {0.f, 0.f};

    const uint4* ksrc_h = (const uint4*)(Kh_g + (size_t)bh * SEQ * INNER);
    const uint4* ksrc_l = (const uint4*)(Kl_g + (size_t)bh * SEQ * INNER);
    const uint4* vsrc_h = (const uint4*)(Vth_g + (size_t)bh * INNER * SEQ);
    const uint4* vsrc_l = (const uint4*)(Vtl_g + (size_t)bh * INNER * SEQ);

    // prefetch tile 0 into registers
    uint4 pkh[2], pkl[2], pvh[2], pvl[2];
#pragma unroll
    for (int ii = 0; ii < 2; ++ii) {
        int id = t + ii * 256, row = id >> 3, part = id & 7;
        pkh[ii] = ksrc_h[id];
        pkl[ii] = ksrc_l[id];
        pvh[ii] = vsrc_h[row * 256 + part];
        pvl[ii] = vsrc_l[row * 256 + part];
    }

    for (int kt = 0; kt < 32; ++kt) {
        __syncthreads();   // (A) prior tile's readers done
#pragma unroll
        for (int ii = 0; ii < 2; ++ii) {
            int id = t + ii * 256, row = id >> 3, part = id & 7;
            int dst = row * 72 + part * 8;
            *(uint4*)&Ksh[dst] = pkh[ii];
            *(uint4*)&Ksl[dst] = pkl[ii];
            *(uint4*)&Vsh[dst] = pvh[ii];
            *(uint4*)&Vsl[dst] = pvl[ii];
        }
        if (kt + 1 < 32) {
#pragma unroll
            for (int ii = 0; ii < 2; ++ii) {
                int id = t + ii * 256, row = id >> 3, part = id & 7;
                pkh[ii] = ksrc_h[(kt + 1) * 512 + id];
                pkl[ii] = ksrc_l[(kt + 1) * 512 + id];
                pvh[ii] = vsrc_h[row * 256 + (kt + 1) * 8 + part];
                pvl[ii] = vsrc_l[row * 256 + (kt + 1) * 8 + part];
            }
        }
        __syncthreads();   // (B) staging visible

        floatx4 s[2][4];
#pragma unroll
        for (int st = 0; st < 4; ++st) {
            const unsigned short* ka = &Ksh[(st * 16 + l16) * 72 + quad * 8];
            const unsigned short* kb = &Ksl[(st * 16 + l16) * 72 + quad * 8];
            short8 kh0 = *(const short8*)ka;
            short8 kh1 = *(const short8*)(ka + 32);
            short8 kl0 = *(const short8*)kb;
            short8 kl1 = *(const short8*)(kb + 32);
#pragma unroll
            for (int qg = 0; qg < 2; ++qg) {
                floatx4 a = (floatx4)(0.f);
                a = __builtin_amdgcn_mfma_f32_16x16x32_bf16(kh0, qhf[qg][0], a, 0, 0, 0);
                a = __builtin_amdgcn_mfma_f32_16x16x32_bf16(kh1, qhf[qg][1], a, 0, 0, 0);
                a = __builtin_amdgcn_mfma_f32_16x16x32_bf16(kl0, qhf[qg][0], a, 0, 0, 0);
                a = __builtin_amdgcn_mfma_f32_16x16x32_bf16(kl1, qhf[qg][1], a, 0, 0, 0);
                a = __builtin_amdgcn_mfma_f32_16x16x32_bf16(kh0, qlf[qg][0], a, 0, 0, 0);
                a = __builtin_amdgcn_mfma_f32_16x16x32_bf16(kh1, qlf[qg][1], a, 0, 0, 0);
                s[qg][st] = a;
            }
        }

#pragma unroll
        for (int qg = 0; qg < 2; ++qg) {
            float mloc = s[qg][0][0];
#pragma unroll
            for (int st = 0; st < 4; ++st)
#pragma unroll
                for (int r = 0; r < 4; ++r) mloc = fmaxf(mloc, s[qg][st][r]);
            mloc = fmaxf(mloc, __shfl_xor(mloc, 16));
            mloc = fmaxf(mloc, __shfl_xor(mloc, 32));
            float mn = fmaxf(mrun[qg], mloc);
            float alpha = __expf(mrun[qg] - mn);
            mrun[qg] = mn;
            float rs = 0.f;
#pragma unroll
            for (int st = 0; st < 4; ++st)
#pragma unroll
                for (int r = 0; r < 4; ++r) {
                    float p = __expf(s[qg][st][r] - mn);
                    s[qg][st][r] = p;
                    rs += p;
                }
            rs += __shfl_xor(rs, 16);
            rs += __shfl_xor(rs, 32);
            lrun[qg] = lrun[qg] * alpha + rs;
#pragma unroll
            for (int nt = 0; nt < 4; ++nt) o[qg][nt] = o[qg][nt] * alpha;
        }

#pragma unroll
        for (int half = 0; half < 2; ++half) {
            asm volatile("" ::: "memory");
#pragma unroll
            for (int qg = 0; qg < 2; ++qg)
#pragma unroll
                for (int st2 = 0; st2 < 2; ++st2) {
                    int st = half * 2 + st2;
                    float4 v = make_float4(s[qg][st][0], s[qg][st][1],
                                           s[qg][st][2], s[qg][st][3]);
                    *(float4*)&pw[(qg * 16 + l16) * 36 + st2 * 16 + quad * 4] = v;
                }
            asm volatile("s_waitcnt lgkmcnt(0)" ::: "memory");

            short8 phf[2], plf[2];
#pragma unroll
            for (int qg = 0; qg < 2; ++qg) {
                const float* pr = &pw[(qg * 16 + l16) * 36 + quad * 8];
                float4 pa = *(const float4*)pr;
                float4 pb = *(const float4*)(pr + 4);
                float pv[8] = {pa.x, pa.y, pa.z, pa.w, pb.x, pb.y, pb.z, pb.w};
#pragma unroll
                for (int jj = 0; jj < 8; ++jj) {
                    unsigned short hu, lu;
                    split_bf(pv[jj], hu, lu);
                    phf[qg][jj] = (short)hu;
                    plf[qg][jj] = (short)lu;
                }
            }
#pragma unroll
            for (int nt = 0; nt < 4; ++nt) {
                const unsigned short* va = &Vsh[(nt * 16 + l16) * 72 + half * 32 + quad * 8];
                const unsigned short* vb = &Vsl[(nt * 16 + l16) * 72 + half * 32 + quad * 8];
                short8 vh = *(const short8*)va;
                short8 vl = *(const short8*)vb;
#pragma unroll
                for (int qg = 0; qg < 2; ++qg) {
                    o[qg][nt] = __builtin_amdgcn_mfma_f32_16x16x32_bf16(vh, phf[qg], o[qg][nt], 0, 0, 0);
                    o[qg][nt] = __builtin_amdgcn_mfma_f32_16x16x32_bf16(vh, plf[qg], o[qg][nt], 0, 0, 0);
                    o[qg][nt] = __builtin_amdgcn_mfma_f32_16x16x32_bf16(vl, phf[qg], o[qg][nt], 0, 0, 0);
                }
            }
        }
    }

    // epilogue: split-bf16 O
#pragma unroll
    for (int qg = 0; qg < 2; ++qg) {
        float inv = 1.f / lrun[qg];
        size_t row = (size_t)bh * SEQ + qbase + qg * 16 + l16;
#pragma unroll
        for (int nt = 0; nt < 4; ++nt) {
            float f[4] = {o[qg][nt][0] * inv, o[qg][nt][1] * inv,
                          o[qg][nt][2] * inv, o[qg][nt][3] * inv};
            uint2 ph, pl;
            split4(f, ph, pl);
            size_t off = row * 64 + nt * 16 + quad * 4;
            *(uint2*)&Oh_g[off] = ph;
            *(uint2*)&Ol_g[off] = pl;
        }
    }
}

// ---------------------------------------------------------------------------
// Kernel 3: output projection, split-bf16 MFMA. Direct staging (no prefetch),
// __launch_bounds__(256,2), XCD swizzle. 64x128 tiles; grid 512 = 2/CU.
// ---------------------------------------------------------------------------
__global__ __launch_bounds__(256, 2) void out_proj_mfma(const unsigned short* __restrict__ Oh,
                                                        const unsigned short* __restrict__ Ol,
                                                        const unsigned short* __restrict__ Hth,
                                                        const unsigned short* __restrict__ Htl,
                                                        float* __restrict__ Y) {
    __shared__ __align__(16) unsigned short smem[12288];   // 24.6 KB
    unsigned short* Ah = smem;            // 64 x 32
    unsigned short* Al = smem + 2048;
    unsigned short* Bh = smem + 4096;     // 128 x 32
    unsigned short* Bl = smem + 8192;

    const int t = threadIdx.x;
    const int w = t >> 6, lane = t & 63;
    const int quad = lane >> 4, l16 = lane & 15;
    const int wm = w & 1, wn = w >> 1;
    const int bid = blockIdx.x;
    const int xcd = bid & 7, rest = bid >> 3;
    const int nb = rest & 3, rsub = rest >> 2;
    const int r0 = (rsub * 8 + xcd) * 64, n0 = nb * 128;
    const int b = r0 >> 11;

    const int arow = t >> 2, apart = t & 3;

    floatx4 acc[2][4];
#pragma unroll
    for (int mt = 0; mt < 2; ++mt)
#pragma unroll
        for (int nt = 0; nt < 4; ++nt) acc[mt][nt] = (floatx4)(0.f);

    for (int ko = 0; ko < 16; ++ko) {
        const int h = ko >> 1, d0 = (ko & 1) * 32;
        const size_t bh = (size_t)b * HEADS + h;
        const int k0 = ko * 32;
        __syncthreads();
        {
            size_t srcA = (bh * SEQ + (r0 & 2047) + arow) * 64 + d0 + apart * 8;
            int dst = arow * 32 + apart * 8;
            *(uint4*)&Ah[dst] = *(const uint4*)&Oh[srcA];
            *(uint4*)&Al[dst] = *(const uint4*)&Ol[srcA];
        }
#pragma unroll
        for (int c = 0; c < 2; ++c) {
            int n = arow + c * 64;
            size_t srcB = (size_t)(n0 + n) * 512 + k0 + apart * 8;
            int dst = n * 32 + apart * 8;
            *(uint4*)&Bh[dst] = *(const uint4*)&Hth[srcB];
            *(uint4*)&Bl[dst] = *(const uint4*)&Htl[srcB];
        }
        __syncthreads();

        short8 af[2], alf[2], bf[4], blf[4];
#pragma unroll
        for (int mt = 0; mt < 2; ++mt) {
            af[mt]  = *(const short8*)&Ah[(wm * 32 + mt * 16 + l16) * 32 + quad * 8];
            alf[mt] = *(const short8*)&Al[(wm * 32 + mt * 16 + l16) * 32 + quad * 8];
        }
#pragma unroll
        for (int nt = 0; nt < 4; ++nt) {
            bf[nt]  = *(const short8*)&Bh[(wn * 64 + nt * 16 + l16) * 32 + quad * 8];
            blf[nt] = *(const short8*)&Bl[(wn * 64 + nt * 16 + l16) * 32 + quad * 8];
        }
#pragma unroll
        for (int mt = 0; mt < 2; ++mt)
#pragma unroll
            for (int nt = 0; nt < 4; ++nt) {
                acc[mt][nt] = __builtin_amdgcn_mfma_f32_16x16x32_bf16(af[mt], bf[nt], acc[mt][nt], 0, 0, 0);
                acc[mt][nt] = __builtin_amdgcn_mfma_f32_16x16x32_bf16(af[mt], blf[nt], acc[mt][nt], 0, 0, 0);
                acc[mt][nt] = __builtin_amdgcn_mfma_f32_16x16x32_bf16(alf[mt], bf[nt], acc[mt][nt], 0, 0, 0);
            }
    }

#pragma unroll
    for (int mt = 0; mt < 2; ++mt)
#pragma unroll
        for (int nt = 0; nt < 4; ++nt)
#pragma unroll
            for (int r = 0; r < 4; ++r)
                Y[(size_t)(r0 + wm * 32 + mt * 16 + quad * 4 + r) * 512 +
                  n0 + wn * 64 + nt * 16 + l16] = acc[mt][nt][r];
}

extern "C" void kernel_launch(void* const* d_in, const int* in_sizes, int n_in,
                              void* d_out, int out_size, void* d_ws, size_t ws_size,
                              hipStream_t stream) {
    const float* x    = (const float*)d_in[0];
    const float* kern = (const float*)d_in[1];
    const float* hk   = (const float*)d_in[2];
    float* y = (float*)d_out;

    unsigned short* Qh  = (unsigned short*)d_ws;
    unsigned short* Ql  = Qh + PER_MAT;
    unsigned short* Kh  = Qh + 2 * PER_MAT;
    unsigned short* Kl  = Qh + 3 * PER_MAT;
    unsigned short* Vth = Qh + 4 * PER_MAT;
    unsigned short* Vtl = Qh + 5 * PER_MAT;
    unsigned short* Oh  = Qh + 6 * PER_MAT;
    unsigned short* Ol  = Qh + 7 * PER_MAT;
    unsigned short* Xh  = Oh;   // alias: X dead before attn writes O
    unsigned short* Xl  = Ol;
    unsigned short* Wth = Qh + 8 * PER_MAT;
    unsigned short* Wtl = Wth + (size_t)1536 * 512;
    unsigned short* Hth = Wtl + (size_t)1536 * 512;
    unsigned short* Htl = Hth + (size_t)512 * 512;

    split_x<<<dim3(2048), 256, 0, stream>>>(x, Xh, Xl);
    split_w<<<dim3(24, 8), 256, 0, stream>>>(kern, Wth, Wtl);
    split_hk<<<dim3(8, 8), 256, 0, stream>>>(hk, Hth, Htl);
    qkv_mfma<<<dim3(768), 256, 0, stream>>>(Xh, Xl, Wth, Wtl, Qh, Ql, Kh, Kl, Vth, Vtl);
    attn_mfma<<<dim3(32, 16), 256, 0, stream>>>(Qh, Ql, Kh, Kl, Vth, Vtl, Oh, Ol);
    out_proj_mfma<<<dim3(512), 256, 0, stream>>>(Oh, Ol, Hth, Htl, y);
}